// Round 1
// baseline (399.944 us; speedup 1.0000x reference)
//
#include <hip/hip_runtime.h>

static constexpr int S_TOT = 1024 * 1024;  // flattened image size
static constexpr int RK = 4;               // rank
static constexpr int NK = 3;               // k = 1..3 contribute to d

// Kernel 1: d[k][r] = dot(z, W[k+1][:, r]) for k=0..2, r=0..3.
// Grid-stride; float4 row loads of W (contiguous 16B per lane), butterfly
// wave reduce, per-wave LDS, one atomicAdd per block per partial.
__global__ __launch_bounds__(256) void dots_kernel(
    const float* __restrict__ z,
    const float* __restrict__ W,     // (20, S, 4) flat; we use k=1..3
    float* __restrict__ dsum) {      // 12 floats, pre-zeroed
  float acc[NK][RK];
#pragma unroll
  for (int k = 0; k < NK; ++k)
#pragma unroll
    for (int r = 0; r < RK; ++r) acc[k][r] = 0.f;

  const int tid = blockIdx.x * blockDim.x + threadIdx.x;
  const int stride = gridDim.x * blockDim.x;
  for (int s = tid; s < S_TOT; s += stride) {
    const float zs = z[s];
#pragma unroll
    for (int k = 0; k < NK; ++k) {
      const float4 w = *reinterpret_cast<const float4*>(
          W + (size_t)(k + 1) * S_TOT * RK + (size_t)s * RK);
      acc[k][0] = fmaf(zs, w.x, acc[k][0]);
      acc[k][1] = fmaf(zs, w.y, acc[k][1]);
      acc[k][2] = fmaf(zs, w.z, acc[k][2]);
      acc[k][3] = fmaf(zs, w.w, acc[k][3]);
    }
  }

  // 64-lane butterfly reduce each of the 12 partials
#pragma unroll
  for (int k = 0; k < NK; ++k)
#pragma unroll
    for (int r = 0; r < RK; ++r) {
      float v = acc[k][r];
#pragma unroll
      for (int off = 32; off > 0; off >>= 1) v += __shfl_xor(v, off, 64);
      acc[k][r] = v;
    }

  __shared__ float lds[4][NK * RK];  // 4 waves per 256-thread block
  const int wave = threadIdx.x >> 6;
  const int lane = threadIdx.x & 63;
  if (lane == 0) {
#pragma unroll
    for (int k = 0; k < NK; ++k)
#pragma unroll
      for (int r = 0; r < RK; ++r) lds[wave][k * RK + r] = acc[k][r];
  }
  __syncthreads();
  if (threadIdx.x < NK * RK) {
    float v = 0.f;
#pragma unroll
    for (int w = 0; w < 4; ++w) v += lds[w][threadIdx.x];
    atomicAdd(&dsum[threadIdx.x], v);
  }
}

// Kernel 2: coef[r] = 2 + d0 + d0*d1 + d0*d1*d2 ; out[s] = W0[s,:]·coef + b[s]
__global__ __launch_bounds__(256) void out_kernel(
    const float* __restrict__ W0,    // (S, 4), k=0 slice of W
    const float* __restrict__ b,
    const float* __restrict__ dsum,  // 12 floats from kernel 1
    float* __restrict__ out) {
  __shared__ float coef[RK];
  if (threadIdx.x < RK) {
    const int r = threadIdx.x;
    const float d0 = dsum[r];
    const float d1 = dsum[RK + r];
    const float d2 = dsum[2 * RK + r];
    const float c1 = d0;
    const float c2 = c1 * d1;
    const float c3 = c2 * d2;
    coef[r] = 2.f + c1 + c2 + c3;
  }
  __syncthreads();
  const float c0 = coef[0], c1 = coef[1], c2 = coef[2], c3 = coef[3];

  const int s = blockIdx.x * blockDim.x + threadIdx.x;  // one row per thread
  if (s >= S_TOT) return;
  const float4 w = *reinterpret_cast<const float4*>(W0 + (size_t)s * RK);
  const float bs = b[s];
  out[s] = fmaf(w.x, c0, fmaf(w.y, c1, fmaf(w.z, c2, fmaf(w.w, c3, bs))));
}

extern "C" void kernel_launch(void* const* d_in, const int* in_sizes, int n_in,
                              void* d_out, int out_size, void* d_ws, size_t ws_size,
                              hipStream_t stream) {
  const float* z = (const float*)d_in[0];
  const float* W = (const float*)d_in[1];  // (20, S, 4)
  const float* b = (const float*)d_in[2];
  float* out = (float*)d_out;
  float* dsum = (float*)d_ws;  // 12 floats

  // ws is poisoned with 0xAA before every timed launch — zero our 12 floats.
  hipMemsetAsync(dsum, 0, NK * RK * sizeof(float), stream);

  dots_kernel<<<2048, 256, 0, stream>>>(z, W, dsum);

  const int threads = 256;
  const int blocks = (S_TOT + threads - 1) / threads;  // 4096
  out_kernel<<<blocks, threads, 0, stream>>>(W /*k=0 slice*/, b, dsum, out);
}